// Round 1
// 1669.346 us; speedup vs baseline: 1.3368x; 1.3368x over previous
//
#include <hip/hip_runtime.h>

// Problem: B=4, S=2048, D=2048, H=16, hs=128.
// Inputs/outputs fp32 (per reference); internal compute bf16 MFMA.
// d_out (fp32): [0, 16777216) ff_o [B,S,D]; [16777216, 50331648) kv [2,B,H,S,hs]
// d_ws  (bf16): [0, 16777216) q [64(bh),2048,128] -> overwritten in-place by attn_o

using floatx4 = __attribute__((ext_vector_type(4))) float;
using short8  = __attribute__((ext_vector_type(8))) short;

#define MFMA_BF16(a, b, c) __builtin_amdgcn_mfma_f32_16x16x32_bf16((a), (b), (c), 0, 0, 0)

static __device__ __forceinline__ unsigned short f2bf(float f) {
    unsigned u = __float_as_uint(f);
    u += 0x7FFF + ((u >> 16) & 1);   // round-to-nearest-even
    return (unsigned short)(u >> 16);
}
// load 8 consecutive floats, convert to 8 bf16
static __device__ __forceinline__ short8 cvt8(const float* p) {
    float4 a = ((const float4*)p)[0];
    float4 b = ((const float4*)p)[1];
    short8 r;
    r[0] = (short)f2bf(a.x); r[1] = (short)f2bf(a.y);
    r[2] = (short)f2bf(a.z); r[3] = (short)f2bf(a.w);
    r[4] = (short)f2bf(b.x); r[5] = (short)f2bf(b.y);
    r[6] = (short)f2bf(b.z); r[7] = (short)f2bf(b.w);
    return r;
}

// ---------------------------------------------------------------------------
// GEMM1: x[8192,2048] @ w_proj[6144,2048]^T + b_proj -> q(bf16 ws), k/v(fp32 out)
// ---------------------------------------------------------------------------
__global__ __launch_bounds__(256) void gemm_qkv_kernel(
    const float* __restrict__ X,     // [8192, 2048]
    const float* __restrict__ W,     // [6144, 2048]
    const float* __restrict__ Bias,  // [6144]
    unsigned short* __restrict__ Qws,// [64, 2048, 128] bf16
    float* __restrict__ KV)          // [2, 64, 2048, 128] fp32
{
    const int K = 2048;
    __shared__ short As[64][72];   // +8 pad: 144B rows, 16B-aligned frags
    __shared__ short Bs[64][72];
    const int n0 = blockIdx.x * 64;
    const int m0 = blockIdx.y * 64;
    const int t = threadIdx.x;
    const int wv = t >> 6;
    const int l = t & 63;
    const int lr = l & 15;
    const int lq = l >> 4;
    const int srow = t >> 2;
    const int scol = (t & 3) << 4;

    floatx4 acc[4] = {{0,0,0,0},{0,0,0,0},{0,0,0,0},{0,0,0,0}};

    const float* gA = X + (size_t)(m0 + srow) * K + scol;
    const float* gB = W + (size_t)(n0 + srow) * K + scol;

    for (int k0 = 0; k0 < K; k0 += 64) {
        short8 a0 = cvt8(gA + k0);
        short8 a1 = cvt8(gA + k0 + 8);
        short8 b0 = cvt8(gB + k0);
        short8 b1 = cvt8(gB + k0 + 8);
        __syncthreads();
        *(short8*)&As[srow][scol]     = a0;
        *(short8*)&As[srow][scol + 8] = a1;
        *(short8*)&Bs[srow][scol]     = b0;
        *(short8*)&Bs[srow][scol + 8] = b1;
        __syncthreads();
#pragma unroll
        for (int kc = 0; kc < 2; ++kc) {
            short8 a = *(const short8*)&As[wv * 16 + lr][kc * 32 + lq * 8];
#pragma unroll
            for (int j = 0; j < 4; ++j) {
                short8 b = *(const short8*)&Bs[j * 16 + lr][kc * 32 + lq * 8];
                acc[j] = MFMA_BF16(a, b, acc[j]);
            }
        }
    }
    // epilogue: C row = m0 + wv*16 + lq*4 + r, col = n0 + j*16 + lr  (m89 layout)
#pragma unroll
    for (int j = 0; j < 4; ++j) {
        int e = n0 + j * 16 + lr;
        int h = e / 384;
        int c = e - h * 384;          // within head: q[0,128) k[128,256) v[256,384)
        float bias = Bias[e];
#pragma unroll
        for (int r = 0; r < 4; ++r) {
            int m = m0 + wv * 16 + lq * 4 + r;
            int b = m >> 11, s = m & 2047;
            float o = acc[j][r] + bias;
            size_t base = (((size_t)(b * 16 + h)) * 2048 + s) * 128;
            if (c < 128)      Qws[base + c] = f2bf(o);
            else if (c < 256) KV[base + (c - 128)] = o;
            else              KV[(size_t)16777216 + base + (c - 256)] = o;
        }
    }
}

// ---------------------------------------------------------------------------
// Flash attention v2: 4 waves x 16 q-rows = 64 q/block; 64-key kv tiles.
// Swapped QK^T (mfma(K,Q) -> S^T) makes softmax lane-local: all 256 threads
// active, reduce across the 4 lq-groups with 2 shfl_xor. Q lives in registers.
// V staged transposed via pair-packed dword writes (2-way bank = free).
// 32 MFMAs/wave per tile, exactly 2 barriers per tile.
// ---------------------------------------------------------------------------
__global__ __launch_bounds__(256) void attn_kernel(
    unsigned short* __restrict__ QA,   // [64, 2048, 128] bf16: q in, attn_o out
    const float* __restrict__ KV)      // [2, 64, 2048, 128] fp32
{
    const int S = 2048;
    __shared__ short Ks[64][136];      // 17408 B, rows 272B (16B-aligned)
    __shared__ short Vt[128][72];      // 18432 B, transposed [d][key], rows 144B
    __shared__ short Pb[4][16][72];    //  9216 B, per-wave P rows
    // total 45056 B -> 3 blocks/CU

    const int bh = blockIdx.y;                 // b*16 + h
    const int qt = gridDim.x - 1 - blockIdx.x; // heavy (diagonal-rich) blocks first
    const int q0 = qt * 64;
    const int t = threadIdx.x;
    const int wv = t >> 6;
    const int l = t & 63;
    const int lr = l & 15;
    const int lq = l >> 4;

    unsigned short* Qp = QA + ((size_t)bh * S + q0) * 128;
    const float* Kp = KV + (size_t)bh * S * 128;
    const float* Vp = KV + (size_t)(64 + bh) * S * 128;

    // Q fragments in registers: wave's 16 rows, B-frag layout [lr][kc*32+lq*8]
    short8 qf[4];
#pragma unroll
    for (int kc = 0; kc < 4; ++kc)
        qf[kc] = *(const short8*)(Qp + (size_t)(wv * 16 + lr) * 128 + kc * 32 + lq * 8);

    float m_i = -1e30f, l_i = 0.0f;            // per lane, for q row = lr (dup x4 lq)
    floatx4 oacc[8];
#pragma unroll
    for (int nt = 0; nt < 8; ++nt) oacc[nt] = (floatx4){0,0,0,0};

    // staging decomposition
    const int kr  = t >> 2;            // K: row 0..63
    const int kc0 = (t & 3) * 32;      // K: 32-float chunk
    const int vkp = t & 31;            // V: key pair (keys 2vkp, 2vkp+1)
    const int vd0 = (t >> 5) * 16;     // V: 16-d chunk

    const int ntiles = qt + 1;         // causal
    for (int it = 0; it < ntiles; ++it) {
        const int kv0 = it * 64;

        // ---- global loads + cvt (before barrier: overlap with prev PV) ----
        const float* krp = Kp + (size_t)(kv0 + kr) * 128 + kc0;
        short8 ks0 = cvt8(krp);
        short8 ks1 = cvt8(krp + 8);
        short8 ks2 = cvt8(krp + 16);
        short8 ks3 = cvt8(krp + 24);
        const float* vap = Vp + (size_t)(kv0 + 2 * vkp) * 128 + vd0;
        short8 va0 = cvt8(vap),       va1 = cvt8(vap + 8);
        short8 vb0 = cvt8(vap + 128), vb1 = cvt8(vap + 136);
        __syncthreads();               // prev tile's MFMA reads of Ks/Vt done
        *(short8*)&Ks[kr][kc0]      = ks0;
        *(short8*)&Ks[kr][kc0 + 8]  = ks1;
        *(short8*)&Ks[kr][kc0 + 16] = ks2;
        *(short8*)&Ks[kr][kc0 + 24] = ks3;
        // transposed V: pack key-pair into one dword -> 2-way (free) b32 writes
#pragma unroll
        for (int dd = 0; dd < 8; ++dd) {
            unsigned w0 = (unsigned)(unsigned short)va0[dd] |
                          ((unsigned)(unsigned short)vb0[dd] << 16);
            unsigned w1 = (unsigned)(unsigned short)va1[dd] |
                          ((unsigned)(unsigned short)vb1[dd] << 16);
            *(unsigned*)&Vt[vd0 + dd][2 * vkp]     = w0;
            *(unsigned*)&Vt[vd0 + 8 + dd][2 * vkp] = w1;
        }
        __syncthreads();

        // ---- QK^T swapped: sacc[mt] = S^T (rows=key, cols=q) ----
        floatx4 sacc[4];
#pragma unroll
        for (int mt = 0; mt < 4; ++mt) sacc[mt] = (floatx4){0,0,0,0};
#pragma unroll
        for (int kc = 0; kc < 4; ++kc) {
#pragma unroll
            for (int mt = 0; mt < 4; ++mt) {
                short8 a = *(const short8*)&Ks[mt * 16 + lr][kc * 32 + lq * 8];
                sacc[mt] = MFMA_BF16(a, qf[kc], sacc[mt]);
            }
        }

        // ---- mask + online softmax, all 64 lanes ----
        // lane holds S[q = q0+wv*16+lr][key = kv0 + mt*16 + lq*4 + r]
        float sv[16];
        const bool diag = (it == qt);
#pragma unroll
        for (int mt = 0; mt < 4; ++mt)
#pragma unroll
            for (int r = 0; r < 4; ++r) {
                float x = sacc[mt][r] * 0.08838834764831845f;  // 1/sqrt(128)
                if (diag && (mt * 16 + lq * 4 + r > wv * 16 + lr)) x = -1e30f;
                sv[mt * 4 + r] = x;
            }
        float mx = sv[0];
#pragma unroll
        for (int j = 1; j < 16; ++j) mx = fmaxf(mx, sv[j]);
        mx = fmaxf(mx, __shfl_xor(mx, 16));
        mx = fmaxf(mx, __shfl_xor(mx, 32));
        float m_new = fmaxf(m_i, mx);
        float alpha = __expf(m_i - m_new);
        m_i = m_new;
        float sum = 0.0f;
        unsigned pw[8];
#pragma unroll
        for (int j = 0; j < 8; ++j) {
            float p0 = __expf(sv[2 * j]     - m_new);
            float p1 = __expf(sv[2 * j + 1] - m_new);
            sum += p0 + p1;
            pw[j] = (unsigned)f2bf(p0) | ((unsigned)f2bf(p1) << 16);
        }
        sum += __shfl_xor(sum, 16);
        sum += __shfl_xor(sum, 32);
        l_i = l_i * alpha + sum;

        // P -> per-wave LDS (A-frag source); within-wave, no barrier needed
#pragma unroll
        for (int mt = 0; mt < 4; ++mt)
            *(uint2*)&Pb[wv][lr][mt * 16 + lq * 4] =
                make_uint2(pw[2 * mt], pw[2 * mt + 1]);

        // ---- rescale O, then PV ----
        float am[4];
#pragma unroll
        for (int r = 0; r < 4; ++r) am[r] = __shfl(alpha, lq * 4 + r);
#pragma unroll
        for (int nt = 0; nt < 8; ++nt)
#pragma unroll
            for (int r = 0; r < 4; ++r) oacc[nt][r] *= am[r];

        short8 pa0 = *(const short8*)&Pb[wv][lr][lq * 8];        // keys  0..31
        short8 pa1 = *(const short8*)&Pb[wv][lr][32 + lq * 8];   // keys 32..63
#pragma unroll
        for (int nt = 0; nt < 8; ++nt) {
            short8 v0 = *(const short8*)&Vt[nt * 16 + lr][lq * 8];
            short8 v1 = *(const short8*)&Vt[nt * 16 + lr][32 + lq * 8];
            oacc[nt] = MFMA_BF16(pa0, v0, oacc[nt]);
            oacc[nt] = MFMA_BF16(pa1, v1, oacc[nt]);
        }
    }

    // ---- epilogue: O row m = lq*4+r, col d = nt*16+lr; divide by l, store bf16 ----
    float lm[4];
#pragma unroll
    for (int r = 0; r < 4; ++r) lm[r] = 1.0f / __shfl(l_i, lq * 4 + r);
#pragma unroll
    for (int nt = 0; nt < 8; ++nt) {
#pragma unroll
        for (int r = 0; r < 4; ++r) {
            int q = wv * 16 + lq * 4 + r;
            Qp[(size_t)q * 128 + nt * 16 + lr] = f2bf(oacc[nt][r] * lm[r]);
        }
    }
}

// ---------------------------------------------------------------------------
// GEMM2: attn_o(bf16 head-major ws) @ w_ff[2048,2048]^T + b_ff -> ff_o (fp32)
// A[m=(b,s)][k=h*128+d] = AOhm[(b*16+h)][s][d]
// ---------------------------------------------------------------------------
__global__ __launch_bounds__(256) void gemm_ff_kernel(
    const unsigned short* __restrict__ AOhm,  // [64, 2048, 128] bf16
    const float* __restrict__ W,              // [2048, 2048]
    const float* __restrict__ Bias,           // [2048]
    float* __restrict__ Out)                  // [8192, 2048]
{
    const int K = 2048;
    __shared__ short As[64][72];
    __shared__ short Bs[64][72];
    const int n0 = blockIdx.x * 64;
    const int m0 = blockIdx.y * 64;
    const int t = threadIdx.x;
    const int wv = t >> 6;
    const int l = t & 63;
    const int lr = l & 15;
    const int lq = l >> 4;
    const int srow = t >> 2;
    const int scol = (t & 3) << 4;

    floatx4 acc[4] = {{0,0,0,0},{0,0,0,0},{0,0,0,0},{0,0,0,0}};

    const int mrow = m0 + srow;
    const int b = mrow >> 11, s = mrow & 2047;
    const unsigned short* gA = AOhm + (size_t)(b * 16) * 262144 + (size_t)s * 128;
    const float* gB = W + (size_t)(n0 + srow) * K + scol;

    for (int k0 = 0; k0 < K; k0 += 64) {
        int kk = k0 + scol;            // 16-aligned; 16|128 so chunk is in one head
        int h = kk >> 7, d = kk & 127;
        const unsigned short* pa = gA + (size_t)h * 262144 + d;
        uint4 av0 = *(const uint4*)(pa);
        uint4 av1 = *(const uint4*)(pa + 8);
        short8 b0 = cvt8(gB + k0);
        short8 b1 = cvt8(gB + k0 + 8);
        __syncthreads();
        *(uint4*)&As[srow][scol]      = av0;
        *(uint4*)&As[srow][scol + 8]  = av1;
        *(short8*)&Bs[srow][scol]     = b0;
        *(short8*)&Bs[srow][scol + 8] = b1;
        __syncthreads();
#pragma unroll
        for (int kc = 0; kc < 2; ++kc) {
            short8 a = *(const short8*)&As[wv * 16 + lr][kc * 32 + lq * 8];
#pragma unroll
            for (int j = 0; j < 4; ++j) {
                short8 b2 = *(const short8*)&Bs[j * 16 + lr][kc * 32 + lq * 8];
                acc[j] = MFMA_BF16(a, b2, acc[j]);
            }
        }
    }
#pragma unroll
    for (int j = 0; j < 4; ++j) {
        int e = n0 + j * 16 + lr;
        float bias = Bias[e];
#pragma unroll
        for (int r = 0; r < 4; ++r) {
            int m = m0 + wv * 16 + lq * 4 + r;
            Out[(size_t)m * 2048 + e] = acc[j][r] + bias;
        }
    }
}

extern "C" void kernel_launch(void* const* d_in, const int* in_sizes, int n_in,
                              void* d_out, int out_size, void* d_ws, size_t ws_size,
                              hipStream_t stream) {
    const float* X  = (const float*)d_in[0];  // x
    const float* Wp = (const float*)d_in[1];  // w_proj
    const float* bp = (const float*)d_in[2];  // b_proj
    const float* Wf = (const float*)d_in[3];  // w_ff
    const float* bf = (const float*)d_in[4];  // b_ff

    float* out = (float*)d_out;
    float* kv  = out + 16777216;              // next_prefix_kv [2,4,16,2048,128] fp32
    unsigned short* Qws = (unsigned short*)d_ws; // q -> attn_o in-place, bf16, 32 MiB

    gemm_qkv_kernel<<<dim3(96, 128), 256, 0, stream>>>(X, Wp, bp, Qws, kv);
    attn_kernel<<<dim3(32, 64), 256, 0, stream>>>(Qws, kv);
    gemm_ff_kernel<<<dim3(32, 128), 256, 0, stream>>>(Qws, Wf, bf, out);
}

// Round 2
// 1200.741 us; speedup vs baseline: 1.8585x; 1.3903x over previous
//
#include <hip/hip_runtime.h>

// Problem: B=4, S=2048, D=2048, H=16, hs=128.
// Inputs/outputs fp32 (per reference); internal compute bf16 MFMA.
// d_out (fp32): [0, 16777216) ff_o [B,S,D]; [16777216, 50331648) kv [2,B,H,S,hs]
//   ff_o region doubles as scratch for Xbf16 (32 MiB) + Wproj bf16 (24 MiB):
//   read only by gemm_qkv, dead before gemm_ff writes ff_o. No liveness overlap.
// d_ws (bf16): [0, 32 MiB) q [64(bh),2048,128] -> overwritten in-place by attn_o;
//   [32 MiB, 40 MiB) W_ff bf16 (only if ws_size permits; else fp32 fallback GEMM).

using floatx4 = __attribute__((ext_vector_type(4))) float;
using short8  = __attribute__((ext_vector_type(8))) short;

#define MFMA_BF16(a, b, c) __builtin_amdgcn_mfma_f32_16x16x32_bf16((a), (b), (c), 0, 0, 0)

static __device__ __forceinline__ unsigned short f2bf(float f) {
    unsigned u = __float_as_uint(f);
    u += 0x7FFF + ((u >> 16) & 1);   // round-to-nearest-even
    return (unsigned short)(u >> 16);
}
// load 8 consecutive floats, convert to 8 bf16
static __device__ __forceinline__ short8 cvt8(const float* p) {
    float4 a = ((const float4*)p)[0];
    float4 b = ((const float4*)p)[1];
    short8 r;
    r[0] = (short)f2bf(a.x); r[1] = (short)f2bf(a.y);
    r[2] = (short)f2bf(a.z); r[3] = (short)f2bf(a.w);
    r[4] = (short)f2bf(b.x); r[5] = (short)f2bf(b.y);
    r[6] = (short)f2bf(b.z); r[7] = (short)f2bf(b.w);
    return r;
}

// async global->LDS, 16B per lane. LDS dest = wave-uniform base + lane*16.
// CK-style: truncate generic LDS pointer to 32-bit offset, readfirstlane to SGPR.
static __device__ __forceinline__ void gld16(const void* g, const void* l) {
    unsigned loff = (unsigned)__builtin_amdgcn_readfirstlane((int)(unsigned)(uintptr_t)l);
    __builtin_amdgcn_global_load_lds(
        (__attribute__((address_space(1))) unsigned*)(uintptr_t)g,
        (__attribute__((address_space(3))) unsigned*)loff,
        16, 0, 0);
}

// ---------------------------------------------------------------------------
// cvt: fp32 -> bf16 bulk conversion (X, W_proj, optionally W_ff)
// ---------------------------------------------------------------------------
__global__ __launch_bounds__(256) void cvt_kernel(
    const float* __restrict__ X, const float* __restrict__ Wp,
    const float* __restrict__ Wf,
    unsigned short* __restrict__ Xb, unsigned short* __restrict__ Wpb,
    unsigned short* __restrict__ Wfb, int doWf)
{
    const int NX = 2097152;            // 16,777,216 / 8
    const int NP = 1572864;            // 12,582,912 / 8
    const int NF = 524288;             //  4,194,304 / 8
    const int total = NX + NP + (doWf ? NF : 0);
    const int stride = gridDim.x * 256;
    for (int g = blockIdx.x * 256 + threadIdx.x; g < total; g += stride) {
        const float* src; unsigned short* dst; int off;
        if (g < NX)           { src = X;  dst = Xb;  off = g; }
        else if (g < NX + NP) { src = Wp; dst = Wpb; off = g - NX; }
        else                  { src = Wf; dst = Wfb; off = g - NX - NP; }
        short8 v = cvt8(src + (size_t)off * 8);
        *(short8*)(dst + (size_t)off * 8) = v;
    }
}

// ---------------------------------------------------------------------------
// GEMM1 (m97 structure): Xb[8192,2048]bf16 @ Wpb[6144,2048]^T + b_proj
//   -> q(bf16 ws), k/v(fp32 out). 128x128 tile, BK=64, global_load_lds.
// ---------------------------------------------------------------------------
__global__ __launch_bounds__(256) void gemm_qkv_kernel(
    const unsigned short* __restrict__ Xb,   // [8192, 2048] bf16
    const unsigned short* __restrict__ Wpb,  // [6144, 2048] bf16
    const float* __restrict__ Bias,          // [6144]
    unsigned short* __restrict__ Qws,        // [64, 2048, 128] bf16
    float* __restrict__ KV)                  // [2, 64, 2048, 128] fp32
{
    const int K = 2048;
    __shared__ unsigned short As[128 * 64];  // linear: required by global_load_lds
    __shared__ unsigned short Bs[128 * 64];
    const int n0 = blockIdx.x * 128;
    const int m0 = blockIdx.y * 128;
    const int t = threadIdx.x;
    const int w = t >> 6, l = t & 63;
    const int lr = l & 15, lq = l >> 4;
    const int wr = w >> 1, wc = w & 1;       // wave -> 64x64 quadrant
    const int srow = l >> 3;                 // staging: 8 lanes per 128B row
    const int scol = (l & 7) * 8;

    floatx4 acc[4][4];
#pragma unroll
    for (int mi = 0; mi < 4; ++mi)
#pragma unroll
        for (int ni = 0; ni < 4; ++ni) acc[mi][ni] = (floatx4){0, 0, 0, 0};

    for (int k0 = 0; k0 < K; k0 += 64) {
        __syncthreads();                     // prev compute done with LDS
#pragma unroll
        for (int i = 0; i < 4; ++i) {
            const int rb = (i * 4 + w) * 8;  // 8 rows per wave-issue
            gld16(Xb  + (size_t)(m0 + rb + srow) * K + k0 + scol, &As[(rb)*64]);
            gld16(Wpb + (size_t)(n0 + rb + srow) * K + k0 + scol, &Bs[(rb)*64]);
        }
        __syncthreads();                     // drains vmcnt -> tiles ready
#pragma unroll
        for (int kc = 0; kc < 2; ++kc) {
            short8 af[4], bg[4];
#pragma unroll
            for (int mi = 0; mi < 4; ++mi)
                af[mi] = *(const short8*)&As[(wr * 64 + mi * 16 + lr) * 64 + kc * 32 + lq * 8];
#pragma unroll
            for (int ni = 0; ni < 4; ++ni)
                bg[ni] = *(const short8*)&Bs[(wc * 64 + ni * 16 + lr) * 64 + kc * 32 + lq * 8];
#pragma unroll
            for (int mi = 0; mi < 4; ++mi)
#pragma unroll
                for (int ni = 0; ni < 4; ++ni)
                    acc[mi][ni] = MFMA_BF16(af[mi], bg[ni], acc[mi][ni]);
        }
    }
    // epilogue: row = m0+wr*64+mi*16+lq*4+r, col = n0+wc*64+ni*16+lr (m89 layout)
#pragma unroll
    for (int ni = 0; ni < 4; ++ni) {
        int e = n0 + wc * 64 + ni * 16 + lr;
        int h = e / 384;
        int c = e - h * 384;                 // q[0,128) k[128,256) v[256,384)
        float bias = Bias[e];
#pragma unroll
        for (int mi = 0; mi < 4; ++mi) {
#pragma unroll
            for (int r = 0; r < 4; ++r) {
                int m = m0 + wr * 64 + mi * 16 + lq * 4 + r;
                int b = m >> 11, s = m & 2047;
                float o = acc[mi][ni][r] + bias;
                size_t base = (((size_t)(b * 16 + h)) * 2048 + s) * 128;
                if (c < 128)      Qws[base + c] = f2bf(o);
                else if (c < 256) KV[base + (c - 128)] = o;
                else              KV[(size_t)16777216 + base + (c - 256)] = o;
            }
        }
    }
}

// ---------------------------------------------------------------------------
// Flash attention: 4 waves x 16 q-rows = 64 q/block; 64-key kv tiles.
// Swapped QK^T (mfma(K,Q) -> S^T): softmax lane-local, all 256 threads active.
// ---------------------------------------------------------------------------
__global__ __launch_bounds__(256) void attn_kernel(
    unsigned short* __restrict__ QA,   // [64, 2048, 128] bf16: q in, attn_o out
    const float* __restrict__ KV)      // [2, 64, 2048, 128] fp32
{
    const int S = 2048;
    __shared__ short Ks[64][136];
    __shared__ short Vt[128][72];
    __shared__ short Pb[4][16][72];

    const int bh = blockIdx.y;
    const int qt = gridDim.x - 1 - blockIdx.x; // heavy blocks first
    const int q0 = qt * 64;
    const int t = threadIdx.x;
    const int wv = t >> 6;
    const int l = t & 63;
    const int lr = l & 15;
    const int lq = l >> 4;

    unsigned short* Qp = QA + ((size_t)bh * S + q0) * 128;
    const float* Kp = KV + (size_t)bh * S * 128;
    const float* Vp = KV + (size_t)(64 + bh) * S * 128;

    short8 qf[4];
#pragma unroll
    for (int kc = 0; kc < 4; ++kc)
        qf[kc] = *(const short8*)(Qp + (size_t)(wv * 16 + lr) * 128 + kc * 32 + lq * 8);

    float m_i = -1e30f, l_i = 0.0f;
    floatx4 oacc[8];
#pragma unroll
    for (int nt = 0; nt < 8; ++nt) oacc[nt] = (floatx4){0, 0, 0, 0};

    const int kr  = t >> 2;
    const int kc0 = (t & 3) * 32;
    const int vkp = t & 31;
    const int vd0 = (t >> 5) * 16;

    const int ntiles = qt + 1;
    for (int it = 0; it < ntiles; ++it) {
        const int kv0 = it * 64;
        const float* krp = Kp + (size_t)(kv0 + kr) * 128 + kc0;
        short8 ks0 = cvt8(krp);
        short8 ks1 = cvt8(krp + 8);
        short8 ks2 = cvt8(krp + 16);
        short8 ks3 = cvt8(krp + 24);
        const float* vap = Vp + (size_t)(kv0 + 2 * vkp) * 128 + vd0;
        short8 va0 = cvt8(vap),       va1 = cvt8(vap + 8);
        short8 vb0 = cvt8(vap + 128), vb1 = cvt8(vap + 136);
        __syncthreads();
        *(short8*)&Ks[kr][kc0]      = ks0;
        *(short8*)&Ks[kr][kc0 + 8]  = ks1;
        *(short8*)&Ks[kr][kc0 + 16] = ks2;
        *(short8*)&Ks[kr][kc0 + 24] = ks3;
#pragma unroll
        for (int dd = 0; dd < 8; ++dd) {
            unsigned w0 = (unsigned)(unsigned short)va0[dd] |
                          ((unsigned)(unsigned short)vb0[dd] << 16);
            unsigned w1 = (unsigned)(unsigned short)va1[dd] |
                          ((unsigned)(unsigned short)vb1[dd] << 16);
            *(unsigned*)&Vt[vd0 + dd][2 * vkp]     = w0;
            *(unsigned*)&Vt[vd0 + 8 + dd][2 * vkp] = w1;
        }
        __syncthreads();

        floatx4 sacc[4];
#pragma unroll
        for (int mt = 0; mt < 4; ++mt) sacc[mt] = (floatx4){0, 0, 0, 0};
#pragma unroll
        for (int kc = 0; kc < 4; ++kc) {
#pragma unroll
            for (int mt = 0; mt < 4; ++mt) {
                short8 a = *(const short8*)&Ks[mt * 16 + lr][kc * 32 + lq * 8];
                sacc[mt] = MFMA_BF16(a, qf[kc], sacc[mt]);
            }
        }

        float sv[16];
        const bool diag = (it == qt);
#pragma unroll
        for (int mt = 0; mt < 4; ++mt)
#pragma unroll
            for (int r = 0; r < 4; ++r) {
                float x = sacc[mt][r] * 0.08838834764831845f;
                if (diag && (mt * 16 + lq * 4 + r > wv * 16 + lr)) x = -1e30f;
                sv[mt * 4 + r] = x;
            }
        float mx = sv[0];
#pragma unroll
        for (int j = 1; j < 16; ++j) mx = fmaxf(mx, sv[j]);
        mx = fmaxf(mx, __shfl_xor(mx, 16));
        mx = fmaxf(mx, __shfl_xor(mx, 32));
        float m_new = fmaxf(m_i, mx);
        float alpha = __expf(m_i - m_new);
        m_i = m_new;
        float sum = 0.0f;
        unsigned pw[8];
#pragma unroll
        for (int j = 0; j < 8; ++j) {
            float p0 = __expf(sv[2 * j]     - m_new);
            float p1 = __expf(sv[2 * j + 1] - m_new);
            sum += p0 + p1;
            pw[j] = (unsigned)f2bf(p0) | ((unsigned)f2bf(p1) << 16);
        }
        sum += __shfl_xor(sum, 16);
        sum += __shfl_xor(sum, 32);
        l_i = l_i * alpha + sum;

#pragma unroll
        for (int mt = 0; mt < 4; ++mt)
            *(uint2*)&Pb[wv][lr][mt * 16 + lq * 4] =
                make_uint2(pw[2 * mt], pw[2 * mt + 1]);

        float am[4];
#pragma unroll
        for (int r = 0; r < 4; ++r) am[r] = __shfl(alpha, lq * 4 + r);
#pragma unroll
        for (int nt = 0; nt < 8; ++nt)
#pragma unroll
            for (int r = 0; r < 4; ++r) oacc[nt][r] *= am[r];

        short8 pa0 = *(const short8*)&Pb[wv][lr][lq * 8];
        short8 pa1 = *(const short8*)&Pb[wv][lr][32 + lq * 8];
#pragma unroll
        for (int nt = 0; nt < 8; ++nt) {
            short8 v0 = *(const short8*)&Vt[nt * 16 + lr][lq * 8];
            short8 v1 = *(const short8*)&Vt[nt * 16 + lr][32 + lq * 8];
            oacc[nt] = MFMA_BF16(pa0, v0, oacc[nt]);
            oacc[nt] = MFMA_BF16(pa1, v1, oacc[nt]);
        }
    }

    float lm[4];
#pragma unroll
    for (int r = 0; r < 4; ++r) lm[r] = 1.0f / __shfl(l_i, lq * 4 + r);
#pragma unroll
    for (int nt = 0; nt < 8; ++nt) {
#pragma unroll
        for (int r = 0; r < 4; ++r) {
            int q = wv * 16 + lq * 4 + r;
            Qp[(size_t)q * 128 + nt * 16 + lr] = f2bf(oacc[nt][r] * lm[r]);
        }
    }
}

// ---------------------------------------------------------------------------
// GEMM2 (m97 structure): attn_o(bf16 head-major ws) @ Wfb[2048,2048]^T + b_ff
// A[m=(b,s)][k=h*128+d] = AOhm[(b*16+h)][s][d]
// ---------------------------------------------------------------------------
__global__ __launch_bounds__(256) void gemm_ff_kernel(
    const unsigned short* __restrict__ AOhm,  // [64, 2048, 128] bf16
    const unsigned short* __restrict__ Wfb,   // [2048, 2048] bf16
    const float* __restrict__ Bias,           // [2048]
    float* __restrict__ Out)                  // [8192, 2048]
{
    const int K = 2048;
    __shared__ unsigned short As[128 * 64];
    __shared__ unsigned short Bs[128 * 64];
    const int n0 = blockIdx.x * 128;
    const int m0 = blockIdx.y * 128;
    const int t = threadIdx.x;
    const int w = t >> 6, l = t & 63;
    const int lr = l & 15, lq = l >> 4;
    const int wr = w >> 1, wc = w & 1;
    const int srow = l >> 3;
    const int scol = (l & 7) * 8;

    floatx4 acc[4][4];
#pragma unroll
    for (int mi = 0; mi < 4; ++mi)
#pragma unroll
        for (int ni = 0; ni < 4; ++ni) acc[mi][ni] = (floatx4){0, 0, 0, 0};

    for (int k0 = 0; k0 < K; k0 += 64) {
        const int h = k0 >> 7, d0 = (k0 & 127) + scol;  // 64 | 128: tile in one head
        __syncthreads();
#pragma unroll
        for (int i = 0; i < 4; ++i) {
            const int rb = (i * 4 + w) * 8;
            const int m = m0 + rb + srow;
            const int b = m >> 11, s = m & 2047;
            gld16(AOhm + ((size_t)(b * 16 + h) * 2048 + s) * 128 + d0, &As[(rb)*64]);
            gld16(Wfb  + (size_t)(n0 + rb + srow) * K + k0 + scol,     &Bs[(rb)*64]);
        }
        __syncthreads();
#pragma unroll
        for (int kc = 0; kc < 2; ++kc) {
            short8 af[4], bg[4];
#pragma unroll
            for (int mi = 0; mi < 4; ++mi)
                af[mi] = *(const short8*)&As[(wr * 64 + mi * 16 + lr) * 64 + kc * 32 + lq * 8];
#pragma unroll
            for (int ni = 0; ni < 4; ++ni)
                bg[ni] = *(const short8*)&Bs[(wc * 64 + ni * 16 + lr) * 64 + kc * 32 + lq * 8];
#pragma unroll
            for (int mi = 0; mi < 4; ++mi)
#pragma unroll
                for (int ni = 0; ni < 4; ++ni)
                    acc[mi][ni] = MFMA_BF16(af[mi], bg[ni], acc[mi][ni]);
        }
    }
#pragma unroll
    for (int ni = 0; ni < 4; ++ni) {
        int e = n0 + wc * 64 + ni * 16 + lr;
        float bias = Bias[e];
#pragma unroll
        for (int mi = 0; mi < 4; ++mi) {
#pragma unroll
            for (int r = 0; r < 4; ++r) {
                int m = m0 + wr * 64 + mi * 16 + lq * 4 + r;
                Out[(size_t)m * 2048 + e] = acc[mi][ni][r] + bias;
            }
        }
    }
}

// ---------------------------------------------------------------------------
// GEMM2 fallback (64^2, fp32 W staging) if ws can't hold Wfb
// ---------------------------------------------------------------------------
__global__ __launch_bounds__(256) void gemm_ff_fb_kernel(
    const unsigned short* __restrict__ AOhm,  // [64, 2048, 128] bf16
    const float* __restrict__ W,              // [2048, 2048]
    const float* __restrict__ Bias,           // [2048]
    float* __restrict__ Out)                  // [8192, 2048]
{
    const int K = 2048;
    __shared__ short As[64][72];
    __shared__ short Bs[64][72];
    const int n0 = blockIdx.x * 64;
    const int m0 = blockIdx.y * 64;
    const int t = threadIdx.x;
    const int wv = t >> 6;
    const int l = t & 63;
    const int lr = l & 15;
    const int lq = l >> 4;
    const int srow = t >> 2;
    const int scol = (t & 3) << 4;

    floatx4 acc[4] = {{0,0,0,0},{0,0,0,0},{0,0,0,0},{0,0,0,0}};

    const int mrow = m0 + srow;
    const int b = mrow >> 11, s = mrow & 2047;
    const unsigned short* gA = AOhm + (size_t)(b * 16) * 262144 + (size_t)s * 128;
    const float* gB = W + (size_t)(n0 + srow) * K + scol;

    for (int k0 = 0; k0 < K; k0 += 64) {
        int kk = k0 + scol;
        int h = kk >> 7, d = kk & 127;
        const unsigned short* pa = gA + (size_t)h * 262144 + d;
        uint4 av0 = *(const uint4*)(pa);
        uint4 av1 = *(const uint4*)(pa + 8);
        short8 b0 = cvt8(gB + k0);
        short8 b1 = cvt8(gB + k0 + 8);
        __syncthreads();
        *(uint4*)&As[srow][scol]      = av0;
        *(uint4*)&As[srow][scol + 8]  = av1;
        *(short8*)&Bs[srow][scol]     = b0;
        *(short8*)&Bs[srow][scol + 8] = b1;
        __syncthreads();
#pragma unroll
        for (int kc = 0; kc < 2; ++kc) {
            short8 a = *(const short8*)&As[wv * 16 + lr][kc * 32 + lq * 8];
#pragma unroll
            for (int j = 0; j < 4; ++j) {
                short8 b2 = *(const short8*)&Bs[j * 16 + lr][kc * 32 + lq * 8];
                acc[j] = MFMA_BF16(a, b2, acc[j]);
            }
        }
    }
#pragma unroll
    for (int j = 0; j < 4; ++j) {
        int e = n0 + j * 16 + lr;
        float bias = Bias[e];
#pragma unroll
        for (int r = 0; r < 4; ++r) {
            int m = m0 + wv * 16 + lq * 4 + r;
            Out[(size_t)m * 2048 + e] = acc[j][r] + bias;
        }
    }
}

extern "C" void kernel_launch(void* const* d_in, const int* in_sizes, int n_in,
                              void* d_out, int out_size, void* d_ws, size_t ws_size,
                              hipStream_t stream) {
    const float* X  = (const float*)d_in[0];  // x
    const float* Wp = (const float*)d_in[1];  // w_proj
    const float* bp = (const float*)d_in[2];  // b_proj
    const float* Wf = (const float*)d_in[3];  // w_ff
    const float* bf = (const float*)d_in[4];  // b_ff

    float* out = (float*)d_out;
    float* kv  = out + 16777216;              // next_prefix_kv [2,4,16,2048,128] fp32
    unsigned short* Qws = (unsigned short*)d_ws; // q -> attn_o in-place, 32 MiB

    // bf16 scratch: X + W_proj in the (currently dead) ff_o region of d_out
    unsigned short* Xb  = (unsigned short*)out;       // 32 MiB
    unsigned short* Wpb = Xb + 16777216;              // 24 MiB (ends < ff_o end)
    const bool wfInWs = ws_size >= (size_t)33554432 + 8388608;
    unsigned short* Wfb = wfInWs ? Qws + 16777216 : (unsigned short*)nullptr;

    cvt_kernel<<<dim3(2048), 256, 0, stream>>>(X, Wp, Wf, Xb, Wpb, Wfb,
                                               wfInWs ? 1 : 0);
    gemm_qkv_kernel<<<dim3(48, 64), 256, 0, stream>>>(Xb, Wpb, bp, Qws, kv);
    attn_kernel<<<dim3(32, 64), 256, 0, stream>>>(Qws, kv);
    if (wfInWs)
        gemm_ff_kernel<<<dim3(16, 64), 256, 0, stream>>>(Qws, Wfb, bf, out);
    else
        gemm_ff_fb_kernel<<<dim3(32, 128), 256, 0, stream>>>(Qws, Wf, bf, out);
}

// Round 3
// 972.559 us; speedup vs baseline: 2.2945x; 1.2346x over previous
//
#include <hip/hip_runtime.h>

// Problem: B=4, S=2048, D=2048, H=16, hs=128.
// Inputs/outputs fp32 (per reference); internal compute bf16 MFMA.
// d_out (fp32): [0, 16777216) ff_o [B,S,D]; [16777216, 50331648) kv [2,B,H,S,hs]
//   ff_o region is scratch until gemm_ff writes it:
//     phase A (cvt):      Xb bf16 [0,32MiB) + Wpb bf16 [32,56MiB)
//     phase C (repack):   Kb bf16 [0,32MiB) + Vtb bf16 [32,64MiB)  (Xb/Wpb dead)
// d_ws (bf16): [0, 32 MiB) q [64(bh),2048,128] -> overwritten in-place by attn_o;
//   [32 MiB, 40 MiB) W_ff bf16 (only if ws_size permits; else fp32 fallback GEMM).

using floatx4 = __attribute__((ext_vector_type(4))) float;
using short8  = __attribute__((ext_vector_type(8))) short;

#define MFMA_BF16(a, b, c) __builtin_amdgcn_mfma_f32_16x16x32_bf16((a), (b), (c), 0, 0, 0)

static __device__ __forceinline__ unsigned short f2bf(float f) {
    unsigned u = __float_as_uint(f);
    u += 0x7FFF + ((u >> 16) & 1);   // round-to-nearest-even
    return (unsigned short)(u >> 16);
}
// load 8 consecutive floats, convert to 8 bf16
static __device__ __forceinline__ short8 cvt8(const float* p) {
    float4 a = ((const float4*)p)[0];
    float4 b = ((const float4*)p)[1];
    short8 r;
    r[0] = (short)f2bf(a.x); r[1] = (short)f2bf(a.y);
    r[2] = (short)f2bf(a.z); r[3] = (short)f2bf(a.w);
    r[4] = (short)f2bf(b.x); r[5] = (short)f2bf(b.y);
    r[6] = (short)f2bf(b.z); r[7] = (short)f2bf(b.w);
    return r;
}

// async global->LDS, 16B per lane. LDS dest = wave-uniform base + lane*16.
static __device__ __forceinline__ void gld16(const void* g, const void* l) {
    unsigned loff = (unsigned)__builtin_amdgcn_readfirstlane((int)(unsigned)(uintptr_t)l);
    __builtin_amdgcn_global_load_lds(
        (__attribute__((address_space(1))) unsigned*)(uintptr_t)g,
        (__attribute__((address_space(3))) unsigned*)loff,
        16, 0, 0);
}

// ---------------------------------------------------------------------------
// cvt: fp32 -> bf16 bulk conversion (X, W_proj, optionally W_ff)
// ---------------------------------------------------------------------------
__global__ __launch_bounds__(256) void cvt_kernel(
    const float* __restrict__ X, const float* __restrict__ Wp,
    const float* __restrict__ Wf,
    unsigned short* __restrict__ Xb, unsigned short* __restrict__ Wpb,
    unsigned short* __restrict__ Wfb, int doWf)
{
    const int NX = 2097152;            // 16,777,216 / 8
    const int NP = 1572864;            // 12,582,912 / 8
    const int NF = 524288;             //  4,194,304 / 8
    const int total = NX + NP + (doWf ? NF : 0);
    const int stride = gridDim.x * 256;
    for (int g = blockIdx.x * 256 + threadIdx.x; g < total; g += stride) {
        const float* src; unsigned short* dst; int off;
        if (g < NX)           { src = X;  dst = Xb;  off = g; }
        else if (g < NX + NP) { src = Wp; dst = Wpb; off = g - NX; }
        else                  { src = Wf; dst = Wfb; off = g - NX - NP; }
        short8 v = cvt8(src + (size_t)off * 8);
        *(short8*)(dst + (size_t)off * 8) = v;
    }
}

// ---------------------------------------------------------------------------
// GEMM1 (m97 structure): Xb[8192,2048]bf16 @ Wpb[6144,2048]^T + b_proj
//   -> q(bf16 ws), k/v(fp32 out). 128x128 tile, BK=64, global_load_lds.
// ---------------------------------------------------------------------------
__global__ __launch_bounds__(256) void gemm_qkv_kernel(
    const unsigned short* __restrict__ Xb,   // [8192, 2048] bf16
    const unsigned short* __restrict__ Wpb,  // [6144, 2048] bf16
    const float* __restrict__ Bias,          // [6144]
    unsigned short* __restrict__ Qws,        // [64, 2048, 128] bf16
    float* __restrict__ KV)                  // [2, 64, 2048, 128] fp32
{
    const int K = 2048;
    __shared__ unsigned short As[128 * 64];  // linear: required by global_load_lds
    __shared__ unsigned short Bs[128 * 64];
    const int n0 = blockIdx.x * 128;
    const int m0 = blockIdx.y * 128;
    const int t = threadIdx.x;
    const int w = t >> 6, l = t & 63;
    const int lr = l & 15, lq = l >> 4;
    const int wr = w >> 1, wc = w & 1;       // wave -> 64x64 quadrant
    const int srow = l >> 3;                 // staging: 8 lanes per 128B row
    const int scol = (l & 7) * 8;

    floatx4 acc[4][4];
#pragma unroll
    for (int mi = 0; mi < 4; ++mi)
#pragma unroll
        for (int ni = 0; ni < 4; ++ni) acc[mi][ni] = (floatx4){0, 0, 0, 0};

    for (int k0 = 0; k0 < K; k0 += 64) {
        __syncthreads();                     // prev compute done with LDS
#pragma unroll
        for (int i = 0; i < 4; ++i) {
            const int rb = (i * 4 + w) * 8;  // 8 rows per wave-issue
            gld16(Xb  + (size_t)(m0 + rb + srow) * K + k0 + scol, &As[(rb)*64]);
            gld16(Wpb + (size_t)(n0 + rb + srow) * K + k0 + scol, &Bs[(rb)*64]);
        }
        __syncthreads();                     // drains vmcnt -> tiles ready
#pragma unroll
        for (int kc = 0; kc < 2; ++kc) {
            short8 af[4], bg[4];
#pragma unroll
            for (int mi = 0; mi < 4; ++mi)
                af[mi] = *(const short8*)&As[(wr * 64 + mi * 16 + lr) * 64 + kc * 32 + lq * 8];
#pragma unroll
            for (int ni = 0; ni < 4; ++ni)
                bg[ni] = *(const short8*)&Bs[(wc * 64 + ni * 16 + lr) * 64 + kc * 32 + lq * 8];
#pragma unroll
            for (int mi = 0; mi < 4; ++mi)
#pragma unroll
                for (int ni = 0; ni < 4; ++ni)
                    acc[mi][ni] = MFMA_BF16(af[mi], bg[ni], acc[mi][ni]);
        }
    }
    // epilogue: row = m0+wr*64+mi*16+lq*4+r, col = n0+wc*64+ni*16+lr (m89 layout)
#pragma unroll
    for (int ni = 0; ni < 4; ++ni) {
        int e = n0 + wc * 64 + ni * 16 + lr;
        int h = e / 384;
        int c = e - h * 384;                 // q[0,128) k[128,256) v[256,384)
        float bias = Bias[e];
#pragma unroll
        for (int mi = 0; mi < 4; ++mi) {
#pragma unroll
            for (int r = 0; r < 4; ++r) {
                int m = m0 + wr * 64 + mi * 16 + lq * 4 + r;
                int b = m >> 11, s = m & 2047;
                float o = acc[mi][ni][r] + bias;
                size_t base = (((size_t)(b * 16 + h)) * 2048 + s) * 128;
                if (c < 128)      Qws[base + c] = f2bf(o);
                else if (c < 256) KV[base + (c - 128)] = o;
                else              KV[(size_t)16777216 + base + (c - 256)] = o;
            }
        }
    }
}

// ---------------------------------------------------------------------------
// repack_kv: fp32 KV -> bf16 Kb (row-major, chunk-swizzled) + Vtb (transposed,
// chunk-swizzled). Runs ONCE; amortizes cvt+transpose over ~16.5 q-tiles.
// Swizzle: 16B chunk index c stored at position c ^ (row&7) within each row's
// 16-chunk (K) / window's 8-chunk (V) span; attn reads with the same XOR.
// ---------------------------------------------------------------------------
__global__ __launch_bounds__(256) void repack_kv_kernel(
    const float* __restrict__ KV,     // [2,64,2048,128] fp32
    unsigned short* __restrict__ Kb,  // [64][2048][128] bf16 swizzled
    unsigned short* __restrict__ Vtb) // [64][128][2048] bf16 transposed+swizzled
{
    __shared__ short Vt[128][72];
    const int bh = blockIdx.x >> 5;
    const int w  = blockIdx.x & 31;        // 64-key window
    const int t  = threadIdx.x;

    // ---- K: rows s = w*64 .. +63, 16 chunks of 8 elems each ----
    {
        const int kr = t >> 2;             // 0..63
        const int c4 = (t & 3) * 4;        // chunks c4..c4+3
        const int s  = w * 64 + kr;
        const float* kp = KV + ((size_t)bh * 2048 + s) * 128 + c4 * 8;
        unsigned short* ko = Kb + ((size_t)bh * 2048 + s) * 128;
        const int sw = s & 7;
#pragma unroll
        for (int j = 0; j < 4; ++j) {
            short8 v = cvt8(kp + j * 8);
            *(short8*)(ko + ((c4 + j) ^ sw) * 8) = v;
        }
    }

    // ---- V: transpose 64 keys x 128 d via LDS (pair-packed dwords) ----
    {
        const int vkp = t & 31;            // key pair (keys 2vkp, 2vkp+1)
        const int vd0 = (t >> 5) * 16;     // 16-d chunk
        const float* vap = KV + (((size_t)64 + bh) * 2048 + w * 64 + 2 * vkp) * 128 + vd0;
        short8 va0 = cvt8(vap),       va1 = cvt8(vap + 8);
        short8 vb0 = cvt8(vap + 128), vb1 = cvt8(vap + 136);
#pragma unroll
        for (int dd = 0; dd < 8; ++dd) {
            unsigned w0 = (unsigned)(unsigned short)va0[dd] |
                          ((unsigned)(unsigned short)vb0[dd] << 16);
            unsigned w1 = (unsigned)(unsigned short)va1[dd] |
                          ((unsigned)(unsigned short)vb1[dd] << 16);
            *(unsigned*)&Vt[vd0 + dd][2 * vkp]     = w0;
            *(unsigned*)&Vt[vd0 + 8 + dd][2 * vkp] = w1;
        }
    }
    __syncthreads();
    // write out: 2 threads per d-row, 4 chunks of 16B each, swizzled in window
    {
        const int d = t >> 1, hf = t & 1;
        unsigned short* vo = Vtb + ((size_t)bh * 128 + d) * 2048 + w * 64;
        const int dw = d & 7;
#pragma unroll
        for (int j = 0; j < 4; ++j) {
            int c = hf * 4 + j;
            uint4 v = *(const uint4*)&Vt[d][c * 8];
            *(uint4*)(vo + (c ^ dw) * 8) = v;
        }
    }
}

// ---------------------------------------------------------------------------
// Flash attention v3: 4 waves x 16 q-rows = 64 q/block; 64-key kv tiles.
// K/V staged bf16 via global_load_lds (DMA, zero VALU), pre-swizzled source +
// XOR on ds_read (rule 21). Swapped QK^T -> lane-local softmax, 256 threads.
// ---------------------------------------------------------------------------
__global__ __launch_bounds__(256) void attn_kernel(
    unsigned short* __restrict__ QA,        // [64, 2048, 128] bf16: q in, o out
    const unsigned short* __restrict__ Kb,  // [64][2048][128] bf16 swizzled
    const unsigned short* __restrict__ Vtb) // [64][128][2048] bf16 T+swizzled
{
    const int S = 2048;
    __shared__ unsigned short Ks[64 * 128]; // 16 KB linear (gld16 dest)
    __shared__ unsigned short Vt[128 * 64]; // 16 KB linear
    __shared__ short Pb[4][16][72];         //  9 KB

    const int bh = blockIdx.y;
    const int qt = gridDim.x - 1 - blockIdx.x; // heavy blocks first
    const int q0 = qt * 64;
    const int t = threadIdx.x;
    const int wv = t >> 6;
    const int l = t & 63;
    const int lr = l & 15;
    const int lq = l >> 4;
    const int lr7 = lr & 7;

    unsigned short* Qp = QA + ((size_t)bh * S + q0) * 128;
    const unsigned short* gK = Kb + (size_t)bh * S * 128;
    const unsigned short* gV = Vtb + (size_t)bh * 128 * S;

    short8 qf[4];
#pragma unroll
    for (int kc = 0; kc < 4; ++kc)
        qf[kc] = *(const short8*)(Qp + (size_t)(wv * 16 + lr) * 128 + kc * 32 + lq * 8);

    float m_i = -1e30f, l_i = 0.0f;
    floatx4 oacc[8];
#pragma unroll
    for (int nt = 0; nt < 8; ++nt) oacc[nt] = (floatx4){0, 0, 0, 0};

    const int ntiles = qt + 1;
    for (int it = 0; it < ntiles; ++it) {
        const int kv0 = it * 64;
        __syncthreads();                    // prev tile's MFMA reads done
        // K tile: contiguous 16 KB; call i+wave wv -> 4 rows (1 KB)
#pragma unroll
        for (int i = 0; i < 4; ++i) {
            const int off = (i * 16 + wv * 4) * 128;         // elements
            gld16(gK + (size_t)kv0 * 128 + off + l * 8, &Ks[off]);
        }
        // V tile: [128 d][64 keys] = 16 KB; global rows strided 4096 B
#pragma unroll
        for (int i = 0; i < 4; ++i) {
            const int ob = (i * 16 + wv * 4) * 256 + l * 16; // byte in tile
            const int d = ob >> 7, rem = ob & 127;
            gld16((const char*)gV + (size_t)d * (S * 2) + kv0 * 2 + rem,
                  (const char*)Vt + (i * 16 + wv * 4) * 256);
        }
        __syncthreads();                    // drains vmcnt -> tiles ready

        // ---- QK^T swapped: sacc[mt] = S^T (rows=key, cols=q) ----
        floatx4 sacc[4];
#pragma unroll
        for (int mt = 0; mt < 4; ++mt) sacc[mt] = (floatx4){0, 0, 0, 0};
#pragma unroll
        for (int kc = 0; kc < 4; ++kc) {
#pragma unroll
            for (int mt = 0; mt < 4; ++mt) {
                short8 a = *(const short8*)
                    &Ks[(mt * 16 + lr) * 128 + ((((kc << 2) | lq) ^ lr7) << 3)];
                sacc[mt] = MFMA_BF16(a, qf[kc], sacc[mt]);
            }
        }

        // ---- mask + online softmax, all 64 lanes ----
        float sv[16];
        const bool diag = (it == qt);
#pragma unroll
        for (int mt = 0; mt < 4; ++mt)
#pragma unroll
            for (int r = 0; r < 4; ++r) {
                float x = sacc[mt][r] * 0.08838834764831845f;
                if (diag && (mt * 16 + lq * 4 + r > wv * 16 + lr)) x = -1e30f;
                sv[mt * 4 + r] = x;
            }
        float mx = sv[0];
#pragma unroll
        for (int j = 1; j < 16; ++j) mx = fmaxf(mx, sv[j]);
        mx = fmaxf(mx, __shfl_xor(mx, 16));
        mx = fmaxf(mx, __shfl_xor(mx, 32));
        float m_new = fmaxf(m_i, mx);
        float alpha = __expf(m_i - m_new);
        m_i = m_new;
        float sum = 0.0f;
        unsigned pw[8];
#pragma unroll
        for (int j = 0; j < 8; ++j) {
            float p0 = __expf(sv[2 * j]     - m_new);
            float p1 = __expf(sv[2 * j + 1] - m_new);
            sum += p0 + p1;
            pw[j] = (unsigned)f2bf(p0) | ((unsigned)f2bf(p1) << 16);
        }
        sum += __shfl_xor(sum, 16);
        sum += __shfl_xor(sum, 32);
        l_i = l_i * alpha + sum;

#pragma unroll
        for (int mt = 0; mt < 4; ++mt)
            *(uint2*)&Pb[wv][lr][mt * 16 + lq * 4] =
                make_uint2(pw[2 * mt], pw[2 * mt + 1]);

        // ---- rescale O, then PV ----
        float am[4];
#pragma unroll
        for (int r = 0; r < 4; ++r) am[r] = __shfl(alpha, lq * 4 + r);
#pragma unroll
        for (int nt = 0; nt < 8; ++nt)
#pragma unroll
            for (int r = 0; r < 4; ++r) oacc[nt][r] *= am[r];

        short8 pa0 = *(const short8*)&Pb[wv][lr][lq * 8];        // keys  0..31
        short8 pa1 = *(const short8*)&Pb[wv][lr][32 + lq * 8];   // keys 32..63
#pragma unroll
        for (int nt = 0; nt < 8; ++nt) {
            const int row = nt * 16 + lr;
            short8 v0 = *(const short8*)&Vt[row * 64 + ((lq ^ lr7) << 3)];
            short8 v1 = *(const short8*)&Vt[row * 64 + (((4 + lq) ^ lr7) << 3)];
            oacc[nt] = MFMA_BF16(pa0, v0, oacc[nt]);
            oacc[nt] = MFMA_BF16(pa1, v1, oacc[nt]);
        }
    }

    float lm[4];
#pragma unroll
    for (int r = 0; r < 4; ++r) lm[r] = 1.0f / __shfl(l_i, lq * 4 + r);
#pragma unroll
    for (int nt = 0; nt < 8; ++nt) {
#pragma unroll
        for (int r = 0; r < 4; ++r) {
            int q = wv * 16 + lq * 4 + r;
            Qp[(size_t)q * 128 + nt * 16 + lr] = f2bf(oacc[nt][r] * lm[r]);
        }
    }
}

// ---------------------------------------------------------------------------
// GEMM2 (m97 structure): attn_o(bf16 head-major ws) @ Wfb[2048,2048]^T + b_ff
// ---------------------------------------------------------------------------
__global__ __launch_bounds__(256) void gemm_ff_kernel(
    const unsigned short* __restrict__ AOhm,  // [64, 2048, 128] bf16
    const unsigned short* __restrict__ Wfb,   // [2048, 2048] bf16
    const float* __restrict__ Bias,           // [2048]
    float* __restrict__ Out)                  // [8192, 2048]
{
    const int K = 2048;
    __shared__ unsigned short As[128 * 64];
    __shared__ unsigned short Bs[128 * 64];
    const int n0 = blockIdx.x * 128;
    const int m0 = blockIdx.y * 128;
    const int t = threadIdx.x;
    const int w = t >> 6, l = t & 63;
    const int lr = l & 15, lq = l >> 4;
    const int wr = w >> 1, wc = w & 1;
    const int srow = l >> 3;
    const int scol = (l & 7) * 8;

    floatx4 acc[4][4];
#pragma unroll
    for (int mi = 0; mi < 4; ++mi)
#pragma unroll
        for (int ni = 0; ni < 4; ++ni) acc[mi][ni] = (floatx4){0, 0, 0, 0};

    for (int k0 = 0; k0 < K; k0 += 64) {
        const int h = k0 >> 7, d0 = (k0 & 127) + scol;  // 64 | 128: tile in one head
        __syncthreads();
#pragma unroll
        for (int i = 0; i < 4; ++i) {
            const int rb = (i * 4 + w) * 8;
            const int m = m0 + rb + srow;
            const int b = m >> 11, s = m & 2047;
            gld16(AOhm + ((size_t)(b * 16 + h) * 2048 + s) * 128 + d0, &As[(rb)*64]);
            gld16(Wfb  + (size_t)(n0 + rb + srow) * K + k0 + scol,     &Bs[(rb)*64]);
        }
        __syncthreads();
#pragma unroll
        for (int kc = 0; kc < 2; ++kc) {
            short8 af[4], bg[4];
#pragma unroll
            for (int mi = 0; mi < 4; ++mi)
                af[mi] = *(const short8*)&As[(wr * 64 + mi * 16 + lr) * 64 + kc * 32 + lq * 8];
#pragma unroll
            for (int ni = 0; ni < 4; ++ni)
                bg[ni] = *(const short8*)&Bs[(wc * 64 + ni * 16 + lr) * 64 + kc * 32 + lq * 8];
#pragma unroll
            for (int mi = 0; mi < 4; ++mi)
#pragma unroll
                for (int ni = 0; ni < 4; ++ni)
                    acc[mi][ni] = MFMA_BF16(af[mi], bg[ni], acc[mi][ni]);
        }
    }
#pragma unroll
    for (int ni = 0; ni < 4; ++ni) {
        int e = n0 + wc * 64 + ni * 16 + lr;
        float bias = Bias[e];
#pragma unroll
        for (int mi = 0; mi < 4; ++mi) {
#pragma unroll
            for (int r = 0; r < 4; ++r) {
                int m = m0 + wr * 64 + mi * 16 + lq * 4 + r;
                Out[(size_t)m * 2048 + e] = acc[mi][ni][r] + bias;
            }
        }
    }
}

// ---------------------------------------------------------------------------
// GEMM2 fallback (64^2, fp32 W staging) if ws can't hold Wfb
// ---------------------------------------------------------------------------
__global__ __launch_bounds__(256) void gemm_ff_fb_kernel(
    const unsigned short* __restrict__ AOhm,  // [64, 2048, 128] bf16
    const float* __restrict__ W,              // [2048, 2048]
    const float* __restrict__ Bias,           // [2048]
    float* __restrict__ Out)                  // [8192, 2048]
{
    const int K = 2048;
    __shared__ short As[64][72];
    __shared__ short Bs[64][72];
    const int n0 = blockIdx.x * 64;
    const int m0 = blockIdx.y * 64;
    const int t = threadIdx.x;
    const int wv = t >> 6;
    const int l = t & 63;
    const int lr = l & 15;
    const int lq = l >> 4;
    const int srow = t >> 2;
    const int scol = (t & 3) << 4;

    floatx4 acc[4] = {{0,0,0,0},{0,0,0,0},{0,0,0,0},{0,0,0,0}};

    const int mrow = m0 + srow;
    const int b = mrow >> 11, s = mrow & 2047;
    const unsigned short* gA = AOhm + (size_t)(b * 16) * 262144 + (size_t)s * 128;
    const float* gB = W + (size_t)(n0 + srow) * K + scol;

    for (int k0 = 0; k0 < K; k0 += 64) {
        int kk = k0 + scol;
        int h = kk >> 7, d = kk & 127;
        const unsigned short* pa = gA + (size_t)h * 262144 + d;
        uint4 av0 = *(const uint4*)(pa);
        uint4 av1 = *(const uint4*)(pa + 8);
        short8 b0 = cvt8(gB + k0);
        short8 b1 = cvt8(gB + k0 + 8);
        __syncthreads();
        *(uint4*)&As[srow][scol]      = av0;
        *(uint4*)&As[srow][scol + 8]  = av1;
        *(short8*)&Bs[srow][scol]     = b0;
        *(short8*)&Bs[srow][scol + 8] = b1;
        __syncthreads();
#pragma unroll
        for (int kc = 0; kc < 2; ++kc) {
            short8 a = *(const short8*)&As[wv * 16 + lr][kc * 32 + lq * 8];
#pragma unroll
            for (int j = 0; j < 4; ++j) {
                short8 b2 = *(const short8*)&Bs[j * 16 + lr][kc * 32 + lq * 8];
                acc[j] = MFMA_BF16(a, b2, acc[j]);
            }
        }
    }
#pragma unroll
    for (int j = 0; j < 4; ++j) {
        int e = n0 + j * 16 + lr;
        float bias = Bias[e];
#pragma unroll
        for (int r = 0; r < 4; ++r) {
            int m = m0 + wv * 16 + lq * 4 + r;
            Out[(size_t)m * 2048 + e] = acc[j][r] + bias;
        }
    }
}

extern "C" void kernel_launch(void* const* d_in, const int* in_sizes, int n_in,
                              void* d_out, int out_size, void* d_ws, size_t ws_size,
                              hipStream_t stream) {
    const float* X  = (const float*)d_in[0];  // x
    const float* Wp = (const float*)d_in[1];  // w_proj
    const float* bp = (const float*)d_in[2];  // b_proj
    const float* Wf = (const float*)d_in[3];  // w_ff
    const float* bf = (const float*)d_in[4];  // b_ff

    float* out = (float*)d_out;
    float* kv  = out + 16777216;              // next_prefix_kv [2,4,16,2048,128] fp32
    unsigned short* Qws = (unsigned short*)d_ws; // q -> attn_o in-place, 32 MiB

    // phase A scratch (out[0,56MiB)): Xb + Wpb
    unsigned short* Xb  = (unsigned short*)out;       // 32 MiB
    unsigned short* Wpb = Xb + 16777216;              // 24 MiB
    // phase C scratch (out[0,64MiB), Xb/Wpb dead after gemm_qkv): Kb + Vtb
    unsigned short* Kbs = (unsigned short*)out;       // 32 MiB
    unsigned short* Vtb = Kbs + 16777216;             // 32 MiB
    const bool wfInWs = ws_size >= (size_t)33554432 + 8388608;
    unsigned short* Wfb = wfInWs ? Qws + 16777216 : (unsigned short*)nullptr;

    cvt_kernel<<<dim3(2048), 256, 0, stream>>>(X, Wp, Wf, Xb, Wpb, Wfb,
                                               wfInWs ? 1 : 0);
    gemm_qkv_kernel<<<dim3(48, 64), 256, 0, stream>>>(Xb, Wpb, bp, Qws, kv);
    repack_kv_kernel<<<dim3(2048), 256, 0, stream>>>(kv, Kbs, Vtb);
    attn_kernel<<<dim3(32, 64), 256, 0, stream>>>(Qws, Kbs, Vtb);
    if (wfInWs)
        gemm_ff_kernel<<<dim3(16, 64), 256, 0, stream>>>(Qws, Wfb, bf, out);
    else
        gemm_ff_fb_kernel<<<dim3(32, 128), 256, 0, stream>>>(Qws, Wf, bf, out);
}